// Round 4
// baseline (243.509 us; speedup 1.0000x reference)
//
#include <hip/hip_runtime.h>

#define B_ 2
#define N_ 512
#define E_ 64
#define G_ 192
#define LIN_IN_ 192

typedef __attribute__((ext_vector_type(8))) short bf16x8;
typedef __attribute__((ext_vector_type(4))) float f32x4;

__device__ __forceinline__ unsigned short f2bf(float x) {
  unsigned u = __float_as_uint(x);
  unsigned r = (u + 0x7FFFu + ((u >> 16) & 1u)) >> 16;
  return (unsigned short)r;
}
__device__ __forceinline__ float sigm(float x) { return 1.f / (1.f + __expf(-x)); }
__device__ __forceinline__ float tanh_f(float x) {
  float e = __expf(-2.f * fabsf(x));
  return copysignf((1.f - e) / (1.f + e), x);
}

// ---------- prep1: Bt rows g: [W2e(64) | V1(64)] bf16 (g<192), then whh bf16 block.
//            V2 = wih·W2h (fp32), ub = wih·b_lin ----------
__global__ __launch_bounds__(64) void prep1(const float* __restrict__ Wlin,
                                            const float* __restrict__ blin,
                                            const float* __restrict__ wih,
                                            const float* __restrict__ whh,
                                            unsigned short* __restrict__ Bt,
                                            float* __restrict__ V2,
                                            float* __restrict__ ub) {
  int g = blockIdx.x;   // 0..383
  int f = threadIdx.x;  // 0..63
  if (g < G_) {
    const float* wr = wih + g * 64;  // uniform -> s_load
    float aw = 0.f, a1 = 0.f, a2 = 0.f;
#pragma unroll
    for (int e = 0; e < 64; ++e) {
      float wv = wr[e];
      a1 += wv * Wlin[e * LIN_IN_ + f];          // V1 = wih·W1
      aw += wv * Wlin[e * LIN_IN_ + 64 + f];     // W2e = wih·We
      a2 += wv * Wlin[e * LIN_IN_ + 128 + f];    // V2 = wih·W2h
    }
    Bt[g * 128 + f] = f2bf(aw);
    Bt[g * 128 + 64 + f] = f2bf(a1);
    V2[g * 64 + f] = a2;
    if (f == 0) {
      float s = 0.f;
      for (int e = 0; e < 64; ++e) s += wr[e] * blin[e];
      ub[g] = s;
    }
  } else {
    int gh = g - G_;
    Bt[24576 + gh * 64 + f] = f2bf(whh[gh * 64 + f]);
  }
}

// ---------- prep2: u2p[row,g] = V2[g,:]·h[row,:] + ub[g] ----------
__global__ __launch_bounds__(192) void prep2(const float* __restrict__ h,
                                             const float* __restrict__ V2,
                                             const float* __restrict__ ub,
                                             float* __restrict__ u2p) {
  int row = blockIdx.x;   // b*N+n
  int g = threadIdx.x;    // 0..191
  const float* hr = h + (size_t)row * 64;  // uniform
  float acc = 0.f;
#pragma unroll
  for (int f = 0; f < 64; ++f) acc += V2[g * 64 + f] * hr[f];
  u2p[(size_t)row * G_ + g] = acc + ub[g];
}

// ---------- fused2: K=128 GEMM [edge|h_j]·[W2e|V1]^T (gi) + K=64 edge·whh^T (gh),
//            then gates. Block = 4 waves × 64 pairs = 256 pairs, i fixed. ----------
__global__ __launch_bounds__(256, 2) void fused2(const float* __restrict__ edge,
                                                 const float* __restrict__ adj,
                                                 const float* __restrict__ h,
                                                 const unsigned short* __restrict__ BtW,
                                                 const float* __restrict__ u2p,
                                                 const float* __restrict__ bih,
                                                 const float* __restrict__ bhh,
                                                 float* __restrict__ out) {
  // LDS: gi-B 192 rows x 256B (49152) | gh-B 192 rows x 128B (24576) = 73728 B
  __shared__ uint4 Bs4[4608];
  char* Bc = (char*)Bs4;
  int tid = threadIdx.x;
  const uint4* src = (const uint4*)BtW;
#pragma unroll
  for (int it = 0; it < 18; ++it) {
    int c = tid + it * 256;
    int dst;
    if (c < 3072) {
      int row = c >> 4;
      dst = row * 256 + (((c & 15) * 16) ^ ((row & 7) << 4));
    } else {
      int cc = c - 3072;
      int row = cc >> 3;
      dst = 49152 + row * 128 + (((cc & 7) * 16) ^ ((row & 7) << 4));
    }
    *(uint4*)(Bc + dst) = src[c];
  }
  __syncthreads();

  int lane = tid & 63, wave = tid >> 6;
  unsigned pbase = blockIdx.x * 256u + wave * 64u;
  int b = pbase >> 18;
  int iN = (pbase >> 9) & 511;
  int j0 = pbase & 511;
  int lr = lane & 15, lg = lane >> 4;

  // A-fragments: s=0,1 edge k=0..63; s=2,3 h[j] k=0..63 (as K blocks 64..127)
  bf16x8 afrag[4][4];
#pragma unroll
  for (int mt = 0; mt < 4; ++mt) {
    const float* er = edge + (size_t)(pbase + mt * 16 + lr) * 64 + lg * 8;
    const float* hr = h + ((size_t)(b * N_ + j0 + mt * 16 + lr)) * 64 + lg * 8;
    float tmp[8];
#pragma unroll
    for (int half = 0; half < 2; ++half) {
      *(float4*)tmp = *(const float4*)(er + half * 32);
      *(float4*)(tmp + 4) = *(const float4*)(er + half * 32 + 4);
      bf16x8 v;
#pragma unroll
      for (int q = 0; q < 8; ++q) v[q] = (short)f2bf(tmp[q]);
      afrag[mt][half] = v;
      *(float4*)tmp = *(const float4*)(hr + half * 32);
      *(float4*)(tmp + 4) = *(const float4*)(hr + half * 32 + 4);
#pragma unroll
      for (int q = 0; q < 8; ++q) v[q] = (short)f2bf(tmp[q]);
      afrag[mt][2 + half] = v;
    }
  }

  float adjv[4][4];
#pragma unroll
  for (int mt = 0; mt < 4; ++mt)
#pragma unroll
    for (int r = 0; r < 4; ++r)
      adjv[mt][r] = adj[pbase + mt * 16 + lg * 4 + r];

  const float* u2r = u2p + ((size_t)(b * N_ + iN)) * G_;

#pragma unroll
  for (int t = 0; t < 4; ++t) {  // output features e = t*16 + lr
    f32x4 gi[3][4], gh[3][4];
    f32x4 zero = {0.f, 0.f, 0.f, 0.f};
#pragma unroll
    for (int q = 0; q < 3; ++q)
#pragma unroll
      for (int mt = 0; mt < 4; ++mt) { gi[q][mt] = zero; gh[q][mt] = zero; }

#pragma unroll
    for (int s = 0; s < 4; ++s)
#pragma unroll
      for (int q = 0; q < 3; ++q) {
        int row = q * 64 + t * 16 + lr;
        bf16x8 bfrag = *(const bf16x8*)(Bc + row * 256 +
                                        ((s * 64 + lg * 16) ^ ((row & 7) << 4)));
#pragma unroll
        for (int mt = 0; mt < 4; ++mt)
          gi[q][mt] = __builtin_amdgcn_mfma_f32_16x16x32_bf16(
              afrag[mt][s], bfrag, gi[q][mt], 0, 0, 0);
      }
#pragma unroll
    for (int s = 0; s < 2; ++s)
#pragma unroll
      for (int q = 0; q < 3; ++q) {
        int row = q * 64 + t * 16 + lr;
        bf16x8 bfrag = *(const bf16x8*)(Bc + 49152 + row * 128 +
                                        ((s * 64 + lg * 16) ^ ((row & 7) << 4)));
#pragma unroll
        for (int mt = 0; mt < 4; ++mt)
          gh[q][mt] = __builtin_amdgcn_mfma_f32_16x16x32_bf16(
              afrag[mt][s], bfrag, gh[q][mt], 0, 0, 0);
      }

    int e = t * 16 + lr;
    float u20 = u2r[e], u21 = u2r[e + 64], u22 = u2r[e + 128];
    float bi0 = bih[e], bi1 = bih[e + 64], bi2 = bih[e + 128];
    float bh0 = bhh[e], bh1 = bhh[e + 64], bh2 = bhh[e + 128];
#pragma unroll
    for (int mt = 0; mt < 4; ++mt) {
#pragma unroll
      for (int r = 0; r < 4; ++r) {
        size_t pair = pbase + mt * 16 + lg * 4 + r;
        float a = adjv[mt][r];
        float gir = a * (u20 + gi[0][mt][r]) + bi0;
        float giz = a * (u21 + gi[1][mt][r]) + bi1;
        float gin = a * (u22 + gi[2][mt][r]) + bi2;
        float ghr = gh[0][mt][r] + bh0;
        float ghz = gh[1][mt][r] + bh1;
        float ghn = gh[2][mt][r] + bh2;
        float rg = sigm(gir + ghr);
        float z = sigm(giz + ghz);
        float n = tanh_f(gin + rg * ghn);
        float ev = edge[pair * 64 + e];
        float y = (1.f - z) * n + z * ev;
        out[pair * 64 + e] = y * sigm(y);
      }
    }
  }
}

// ================= fallback fp32 path (used only if ws too small) =================
__global__ __launch_bounds__(64) void mkernelF(const float* __restrict__ edge,
                                               const float* __restrict__ adj,
                                               const float* __restrict__ Wlin,
                                               const float* __restrict__ blin,
                                               const float* __restrict__ h,
                                               float* __restrict__ mout) {
  size_t p = (size_t)blockIdx.x * 64 + threadIdx.x;
  int b = (int)(p >> 18), i = (int)((p >> 9) & 511), j = (int)(p & 511);
  float ed[E_], hj[E_], hi[E_];
  const float4* ep = (const float4*)(edge + p * E_);
  const float4* hjp = (const float4*)(h + ((size_t)(b * N_ + j)) * E_);
  const float4* hip = (const float4*)(h + ((size_t)(b * N_ + i)) * E_);
#pragma unroll
  for (int k = 0; k < E_ / 4; ++k) {
    float4 v = ep[k];
    ed[4 * k] = v.x; ed[4 * k + 1] = v.y; ed[4 * k + 2] = v.z; ed[4 * k + 3] = v.w;
    float4 a = hjp[k];
    hj[4 * k] = a.x; hj[4 * k + 1] = a.y; hj[4 * k + 2] = a.z; hj[4 * k + 3] = a.w;
    float4 u = hip[k];
    hi[4 * k] = u.x; hi[4 * k + 1] = u.y; hi[4 * k + 2] = u.z; hi[4 * k + 3] = u.w;
  }
  float av = adj[p];
  float* mo = mout + p * E_;
  for (int e = 0; e < E_; ++e) {
    const float* w = Wlin + e * LIN_IN_;
    float acc = blin[e];
#pragma unroll
    for (int k = 0; k < E_; ++k)
      acc += hj[k] * w[k] + ed[k] * w[64 + k] + hi[k] * w[128 + k];
    mo[e] = av * acc;
  }
}
__global__ __launch_bounds__(64) void gkernelF(const float* __restrict__ edge,
                                               const float* mbuf,
                                               const float* __restrict__ wih,
                                               const float* __restrict__ whh,
                                               const float* __restrict__ bih,
                                               const float* __restrict__ bhh,
                                               float* out) {
  size_t p = (size_t)blockIdx.x * 64 + threadIdx.x;
  float ed[E_], m[E_];
  const float4* ep = (const float4*)(edge + p * E_);
  const float4* mp = (const float4*)(mbuf + p * E_);
#pragma unroll
  for (int k = 0; k < E_ / 4; ++k) {
    float4 v = ep[k];
    ed[4 * k] = v.x; ed[4 * k + 1] = v.y; ed[4 * k + 2] = v.z; ed[4 * k + 3] = v.w;
    float4 u = mp[k];
    m[4 * k] = u.x; m[4 * k + 1] = u.y; m[4 * k + 2] = u.z; m[4 * k + 3] = u.w;
  }
  float* op = out + p * E_;
  for (int e = 0; e < E_; ++e) {
    const float* wr = wih + e * 64;
    const float* wz = wih + (64 + e) * 64;
    const float* wn = wih + (128 + e) * 64;
    const float* vr = whh + e * 64;
    const float* vz = whh + (64 + e) * 64;
    const float* vn = whh + (128 + e) * 64;
    float ir = bih[e], iz = bih[64 + e], inn = bih[128 + e];
    float hr = bhh[e], hz = bhh[64 + e], hn = bhh[128 + e];
#pragma unroll
    for (int k = 0; k < E_; ++k) {
      float mk = m[k], ek = ed[k];
      ir += mk * wr[k]; iz += mk * wz[k]; inn += mk * wn[k];
      hr += ek * vr[k]; hz += ek * vz[k]; hn += ek * vn[k];
    }
    float r = sigm(ir + hr);
    float z = sigm(iz + hz);
    float nv = tanh_f(inn + r * hn);
    float nh = (1.f - z) * nv + z * ed[e];
    op[e] = nh * sigm(nh);
  }
}

extern "C" void kernel_launch(void* const* d_in, const int* in_sizes, int n_in,
                              void* d_out, int out_size, void* d_ws, size_t ws_size,
                              hipStream_t stream) {
  const float* h    = (const float*)d_in[0];
  const float* edge = (const float*)d_in[1];
  const float* adj  = (const float*)d_in[2];
  const float* Wlin = (const float*)d_in[3];
  const float* blin = (const float*)d_in[4];
  const float* wih  = (const float*)d_in[5];
  const float* whh  = (const float*)d_in[6];
  const float* bih  = (const float*)d_in[7];
  const float* bhh  = (const float*)d_in[8];
  float* out = (float*)d_out;

  // ws layout (bytes): Bt bf16 73728 | V2 49152 | ub 768 + pad | u2p 786432
  const size_t OFF_V2 = 73728, OFF_UB = 122880, OFF_U2 = 123648;
  const size_t WS_NEEDED = OFF_U2 + 786432;
  if (ws_size >= WS_NEEDED) {
    char* w = (char*)d_ws;
    unsigned short* Bt = (unsigned short*)w;
    float* V2 = (float*)(w + OFF_V2);
    float* ub = (float*)(w + OFF_UB);
    float* u2p = (float*)(w + OFF_U2);
    prep1<<<384, 64, 0, stream>>>(Wlin, blin, wih, whh, Bt, V2, ub);
    prep2<<<B_ * N_, 192, 0, stream>>>(h, V2, ub, u2p);
    fused2<<<(B_ * N_ * N_) / 256, 256, 0, stream>>>(edge, adj, h, Bt, u2p,
                                                     bih, bhh, out);
  } else {
    size_t npairs = (size_t)B_ * N_ * N_;
    int blocks = (int)(npairs / 64);
    mkernelF<<<blocks, 64, 0, stream>>>(edge, adj, Wlin, blin, h, out);
    gkernelF<<<blocks, 64, 0, stream>>>(edge, out, wih, whh, bih, bhh, out);
  }
}

// Round 5
// 240.533 us; speedup vs baseline: 1.0124x; 1.0124x over previous
//
#include <hip/hip_runtime.h>

#define B_ 2
#define N_ 512
#define E_ 64
#define G_ 192
#define LIN_IN_ 192

typedef __attribute__((ext_vector_type(8))) short bf16x8;
typedef __attribute__((ext_vector_type(4))) float f32x4;

__device__ __forceinline__ unsigned short f2bf(float x) {
  unsigned u = __float_as_uint(x);
  unsigned r = (u + 0x7FFFu + ((u >> 16) & 1u)) >> 16;
  return (unsigned short)r;
}
__device__ __forceinline__ float sigm(float x) { return 1.f / (1.f + __expf(-x)); }
__device__ __forceinline__ float tanh_f(float x) {
  float e = __expf(-2.f * fabsf(x));
  return copysignf((1.f - e) / (1.f + e), x);
}

// ---------- prep1: Bt[384][64] bf16 = [W2e (wih·We) ; whh]; V1 = wih·W1,
//            V2 = wih·W2h (fp32); ub = wih·b_lin ----------
__global__ __launch_bounds__(64) void prep1(const float* __restrict__ Wlin,
                                            const float* __restrict__ blin,
                                            const float* __restrict__ wih,
                                            const float* __restrict__ whh,
                                            unsigned short* __restrict__ Bt,
                                            float* __restrict__ V1,
                                            float* __restrict__ V2,
                                            float* __restrict__ ub) {
  int g = blockIdx.x;   // 0..383
  int f = threadIdx.x;  // 0..63
  if (g < G_) {
    const float* wr = wih + g * 64;  // uniform -> s_load
    float aw = 0.f, a1 = 0.f, a2 = 0.f;
#pragma unroll
    for (int e = 0; e < 64; ++e) {
      float wv = wr[e];
      a1 += wv * Wlin[e * LIN_IN_ + f];          // V1 = wih·W1
      aw += wv * Wlin[e * LIN_IN_ + 64 + f];     // W2e = wih·We
      a2 += wv * Wlin[e * LIN_IN_ + 128 + f];    // V2 = wih·W2h
    }
    Bt[g * 64 + f] = f2bf(aw);
    V1[g * 64 + f] = a1;
    V2[g * 64 + f] = a2;
    if (f == 0) {
      float s = 0.f;
      for (int e = 0; e < 64; ++e) s += wr[e] * blin[e];
      ub[g] = s;
    }
  } else {
    int gh = g - G_;
    Bt[g * 64 + f] = f2bf(whh[gh * 64 + f]);
  }
}

// ---------- prep2: u1[row,g] = V1[g,:]·h[row,:]; u2p[row,g] = V2[g,:]·h[row,:] + ub[g] ----------
__global__ __launch_bounds__(192) void prep2(const float* __restrict__ h,
                                             const float* __restrict__ V1,
                                             const float* __restrict__ V2,
                                             const float* __restrict__ ub,
                                             float* __restrict__ u1,
                                             float* __restrict__ u2p) {
  int row = blockIdx.x;   // b*N+n
  int g = threadIdx.x;    // 0..191
  const float* hr = h + (size_t)row * 64;  // uniform
  float a1 = 0.f, a2 = 0.f;
#pragma unroll
  for (int f = 0; f < 64; ++f) {
    float hv = hr[f];
    a1 += V1[g * 64 + f] * hv;
    a2 += V2[g * 64 + f] * hv;
  }
  u1[(size_t)row * G_ + g] = a1;
  u2p[(size_t)row * G_ + g] = a2 + ub[g];
}

// ---------- fusedT: D^T = [W2e; whh](384x64) · edge^T. D-tile (M=gate rows,
// N=pairs): thread holds 4 consecutive features x 4 pairs -> float4 epilogue.
// Block = 4 waves x 64 pairs = 256 pairs, i fixed per block half. ----------
__global__ __launch_bounds__(256, 3) void fusedT(const float* __restrict__ edge,
                                                 const float* __restrict__ adj,
                                                 const unsigned short* __restrict__ BtW,
                                                 const float* __restrict__ u1,
                                                 const float* __restrict__ u2p,
                                                 const float* __restrict__ bih,
                                                 const float* __restrict__ bhh,
                                                 float* __restrict__ out) {
  __shared__ uint4 Bs4[3072];  // 48 KB: 384 rows x 128B, XOR-swizzled
  char* Bc = (char*)Bs4;
  int tid = threadIdx.x;
  const uint4* src = (const uint4*)BtW;
#pragma unroll
  for (int it = 0; it < 12; ++it) {
    int c = tid + it * 256;          // 3072 chunks of 16B
    int row = c >> 3;
    *(uint4*)(Bc + row * 128 + (((c & 7) * 16) ^ ((row & 7) << 4))) = src[c];
  }
  __syncthreads();

  int lane = tid & 63, wave = tid >> 6;
  unsigned pbase = blockIdx.x * 256u + wave * 64u;
  int b = pbase >> 18;
  int iN = (pbase >> 9) & 511;
  int j0w = pbase & 511;
  int lr = lane & 15, lg = lane >> 4;

  // B-frags: edge^T — lane holds edge[pair = np*16+lr][k = s*32 + lg*8 + q]
  bf16x8 efrag[4][2];
  float adjv[4];
#pragma unroll
  for (int np = 0; np < 4; ++np) {
    const float* er = edge + (size_t)(pbase + np * 16 + lr) * 64 + lg * 8;
    float tmp[8];
#pragma unroll
    for (int s = 0; s < 2; ++s) {
      *(float4*)tmp = *(const float4*)(er + s * 32);
      *(float4*)(tmp + 4) = *(const float4*)(er + s * 32 + 4);
      bf16x8 v;
#pragma unroll
      for (int q = 0; q < 8; ++q) v[q] = (short)f2bf(tmp[q]);
      efrag[np][s] = v;
    }
    adjv[np] = adj[pbase + np * 16 + lr];
  }

  const float* u2r = u2p + ((size_t)(b * N_ + iN)) * G_;
  const float* u1b = u1 + ((size_t)(b * N_ + j0w)) * G_;

#pragma unroll
  for (int mg = 0; mg < 4; ++mg) {   // feature block: e = mg*16 + lg*4 + reg
    int e0 = mg * 16 + lg * 4;
    // A-frags from LDS: 6 M-tiles {gi_r, gi_z, gi_n, gh_r, gh_z, gh_n}
    bf16x8 wfrag[6][2];
    const int tiles[6] = {mg, mg + 4, mg + 8, mg + 12, mg + 16, mg + 20};
#pragma unroll
    for (int w = 0; w < 6; ++w) {
      int R = tiles[w] * 16 + lr;
#pragma unroll
      for (int s = 0; s < 2; ++s)
        wfrag[w][s] = *(const bf16x8*)(Bc + R * 128 +
                                       ((s * 64 + lg * 16) ^ ((R & 7) << 4)));
    }
    float u2a[3][4], bia[3][4], bha[3][4];
#pragma unroll
    for (int g = 0; g < 3; ++g) {
      *(float4*)u2a[g] = *(const float4*)(u2r + g * 64 + e0);
      *(float4*)bia[g] = *(const float4*)(bih + g * 64 + e0);
      *(float4*)bha[g] = *(const float4*)(bhh + g * 64 + e0);
    }
#pragma unroll
    for (int np = 0; np < 4; ++np) {
      f32x4 acc[6];
      f32x4 zero = {0.f, 0.f, 0.f, 0.f};
#pragma unroll
      for (int w = 0; w < 6; ++w) acc[w] = zero;
#pragma unroll
      for (int s = 0; s < 2; ++s)
#pragma unroll
        for (int w = 0; w < 6; ++w)
          acc[w] = __builtin_amdgcn_mfma_f32_16x16x32_bf16(
              wfrag[w][s], efrag[np][s], acc[w], 0, 0, 0);

      size_t P = pbase + np * 16 + lr;
      const float* u1r = u1b + (size_t)(np * 16 + lr) * G_;
      float u1v[3][4], eva[4], yo[4];
#pragma unroll
      for (int g = 0; g < 3; ++g)
        *(float4*)u1v[g] = *(const float4*)(u1r + g * 64 + e0);
      *(float4*)eva = *(const float4*)(edge + P * 64 + e0);
      float a = adjv[np];
#pragma unroll
      for (int reg = 0; reg < 4; ++reg) {
        float gir = a * (acc[0][reg] + u1v[0][reg] + u2a[0][reg]) + bia[0][reg];
        float giz = a * (acc[1][reg] + u1v[1][reg] + u2a[1][reg]) + bia[1][reg];
        float gin = a * (acc[2][reg] + u1v[2][reg] + u2a[2][reg]) + bia[2][reg];
        float ghr = acc[3][reg] + bha[0][reg];
        float ghz = acc[4][reg] + bha[1][reg];
        float ghn = acc[5][reg] + bha[2][reg];
        float r = sigm(gir + ghr);
        float z = sigm(giz + ghz);
        float n = tanh_f(gin + r * ghn);
        float y = (1.f - z) * n + z * eva[reg];
        yo[reg] = y * sigm(y);
      }
      *(float4*)(out + P * 64 + e0) = *(float4*)yo;
    }
  }
}

// ================= fallback fp32 path (used only if ws too small) =================
__global__ __launch_bounds__(64) void mkernelF(const float* __restrict__ edge,
                                               const float* __restrict__ adj,
                                               const float* __restrict__ Wlin,
                                               const float* __restrict__ blin,
                                               const float* __restrict__ h,
                                               float* __restrict__ mout) {
  size_t p = (size_t)blockIdx.x * 64 + threadIdx.x;
  int b = (int)(p >> 18), i = (int)((p >> 9) & 511), j = (int)(p & 511);
  float ed[E_], hj[E_], hi[E_];
  const float4* ep = (const float4*)(edge + p * E_);
  const float4* hjp = (const float4*)(h + ((size_t)(b * N_ + j)) * E_);
  const float4* hip = (const float4*)(h + ((size_t)(b * N_ + i)) * E_);
#pragma unroll
  for (int k = 0; k < E_ / 4; ++k) {
    float4 v = ep[k];
    ed[4 * k] = v.x; ed[4 * k + 1] = v.y; ed[4 * k + 2] = v.z; ed[4 * k + 3] = v.w;
    float4 a = hjp[k];
    hj[4 * k] = a.x; hj[4 * k + 1] = a.y; hj[4 * k + 2] = a.z; hj[4 * k + 3] = a.w;
    float4 u = hip[k];
    hi[4 * k] = u.x; hi[4 * k + 1] = u.y; hi[4 * k + 2] = u.z; hi[4 * k + 3] = u.w;
  }
  float av = adj[p];
  float* mo = mout + p * E_;
  for (int e = 0; e < E_; ++e) {
    const float* w = Wlin + e * LIN_IN_;
    float acc = blin[e];
#pragma unroll
    for (int k = 0; k < E_; ++k)
      acc += hj[k] * w[k] + ed[k] * w[64 + k] + hi[k] * w[128 + k];
    mo[e] = av * acc;
  }
}
__global__ __launch_bounds__(64) void gkernelF(const float* __restrict__ edge,
                                               const float* mbuf,
                                               const float* __restrict__ wih,
                                               const float* __restrict__ whh,
                                               const float* __restrict__ bih,
                                               const float* __restrict__ bhh,
                                               float* out) {
  size_t p = (size_t)blockIdx.x * 64 + threadIdx.x;
  float ed[E_], m[E_];
  const float4* ep = (const float4*)(edge + p * E_);
  const float4* mp = (const float4*)(mbuf + p * E_);
#pragma unroll
  for (int k = 0; k < E_ / 4; ++k) {
    float4 v = ep[k];
    ed[4 * k] = v.x; ed[4 * k + 1] = v.y; ed[4 * k + 2] = v.z; ed[4 * k + 3] = v.w;
    float4 u = mp[k];
    m[4 * k] = u.x; m[4 * k + 1] = u.y; m[4 * k + 2] = u.z; m[4 * k + 3] = u.w;
  }
  float* op = out + p * E_;
  for (int e = 0; e < E_; ++e) {
    const float* wr = wih + e * 64;
    const float* wz = wih + (64 + e) * 64;
    const float* wn = wih + (128 + e) * 64;
    const float* vr = whh + e * 64;
    const float* vz = whh + (64 + e) * 64;
    const float* vn = whh + (128 + e) * 64;
    float ir = bih[e], iz = bih[64 + e], inn = bih[128 + e];
    float hr = bhh[e], hz = bhh[64 + e], hn = bhh[128 + e];
#pragma unroll
    for (int k = 0; k < E_; ++k) {
      float mk = m[k], ek = ed[k];
      ir += mk * wr[k]; iz += mk * wz[k]; inn += mk * wn[k];
      hr += ek * vr[k]; hz += ek * vz[k]; hn += ek * vn[k];
    }
    float r = sigm(ir + hr);
    float z = sigm(iz + hz);
    float nv = tanh_f(inn + r * hn);
    float nh = (1.f - z) * nv + z * ed[e];
    op[e] = nh * sigm(nh);
  }
}

extern "C" void kernel_launch(void* const* d_in, const int* in_sizes, int n_in,
                              void* d_out, int out_size, void* d_ws, size_t ws_size,
                              hipStream_t stream) {
  const float* h    = (const float*)d_in[0];
  const float* edge = (const float*)d_in[1];
  const float* adj  = (const float*)d_in[2];
  const float* Wlin = (const float*)d_in[3];
  const float* blin = (const float*)d_in[4];
  const float* wih  = (const float*)d_in[5];
  const float* whh  = (const float*)d_in[6];
  const float* bih  = (const float*)d_in[7];
  const float* bhh  = (const float*)d_in[8];
  float* out = (float*)d_out;

  // ws layout (bytes): Bt bf16 49152 | V1 49152 | V2 49152 | ub 1024 | u1 786432 | u2p 786432
  const size_t OFF_V1 = 49152, OFF_V2 = 98304, OFF_UB = 147456,
               OFF_U1 = 148480, OFF_U2 = 148480 + 786432;
  const size_t WS_NEEDED = OFF_U2 + 786432;
  if (ws_size >= WS_NEEDED) {
    char* w = (char*)d_ws;
    unsigned short* Bt = (unsigned short*)w;
    float* V1 = (float*)(w + OFF_V1);
    float* V2 = (float*)(w + OFF_V2);
    float* ub = (float*)(w + OFF_UB);
    float* u1 = (float*)(w + OFF_U1);
    float* u2p = (float*)(w + OFF_U2);
    prep1<<<384, 64, 0, stream>>>(Wlin, blin, wih, whh, Bt, V1, V2, ub);
    prep2<<<B_ * N_, 192, 0, stream>>>(h, V1, V2, ub, u1, u2p);
    fusedT<<<(B_ * N_ * N_) / 256, 256, 0, stream>>>(edge, adj, Bt, u1, u2p,
                                                     bih, bhh, out);
  } else {
    size_t npairs = (size_t)B_ * N_ * N_;
    int blocks = (int)(npairs / 64);
    mkernelF<<<blocks, 64, 0, stream>>>(edge, adj, Wlin, blin, h, out);
    gkernelF<<<blocks, 64, 0, stream>>>(edge, out, wih, whh, bih, bhh, out);
  }
}

// Round 6
// 148.778 us; speedup vs baseline: 1.6367x; 1.6167x over previous
//
#include <hip/hip_runtime.h>
#include <hip/hip_bf16.h>

#define B_ 2
#define N_ 512
#define E_ 64
#define G_ 192
#define LIN_IN_ 192

typedef __attribute__((ext_vector_type(8))) short bf16x8;
typedef __attribute__((ext_vector_type(4))) float f32x4;

__device__ __forceinline__ unsigned short f2bf(float x) {
  unsigned u = __float_as_uint(x);
  unsigned r = (u + 0x7FFFu + ((u >> 16) & 1u)) >> 16;
  return (unsigned short)r;
}
__device__ __forceinline__ float sigm(float x) { return 1.f / (1.f + __expf(-x)); }
__device__ __forceinline__ float tanh_f(float x) {
  float e = __expf(-2.f * fabsf(x));
  return copysignf((1.f - e) / (1.f + e), x);
}
__device__ __forceinline__ bf16x8 pack8(const float* t) {
  union { bf16x8 v; __hip_bfloat16 h[8]; } u;
#pragma unroll
  for (int k = 0; k < 8; ++k) u.h[k] = __float2bfloat16(t[k]);
  return u.v;
}

// ---------- prep1: Bt[384][64] bf16 = [W2e (wih·We) ; whh]; V1 = wih·W1,
//            V2 = wih·W2h (fp32); ub = wih·b_lin ----------
__global__ __launch_bounds__(64) void prep1(const float* __restrict__ Wlin,
                                            const float* __restrict__ blin,
                                            const float* __restrict__ wih,
                                            const float* __restrict__ whh,
                                            unsigned short* __restrict__ Bt,
                                            float* __restrict__ V1,
                                            float* __restrict__ V2,
                                            float* __restrict__ ub) {
  int g = blockIdx.x;   // 0..383
  int f = threadIdx.x;  // 0..63
  if (g < G_) {
    const float* wr = wih + g * 64;  // uniform -> s_load
    float aw = 0.f, a1 = 0.f, a2 = 0.f;
#pragma unroll
    for (int e = 0; e < 64; ++e) {
      float wv = wr[e];
      a1 += wv * Wlin[e * LIN_IN_ + f];          // V1 = wih·W1
      aw += wv * Wlin[e * LIN_IN_ + 64 + f];     // W2e = wih·We
      a2 += wv * Wlin[e * LIN_IN_ + 128 + f];    // V2 = wih·W2h
    }
    Bt[g * 64 + f] = f2bf(aw);
    V1[g * 64 + f] = a1;
    V2[g * 64 + f] = a2;
    if (f == 0) {
      float s = 0.f;
      for (int e = 0; e < 64; ++e) s += wr[e] * blin[e];
      ub[g] = s;
    }
  } else {
    int gh = g - G_;
    Bt[g * 64 + f] = f2bf(whh[gh * 64 + f]);
  }
}

// ---------- prep2: u1[row,g] = V1[g,:]·h[row,:]; u2p[row,g] = V2[g,:]·h[row,:] + ub[g] ----------
__global__ __launch_bounds__(192) void prep2(const float* __restrict__ h,
                                             const float* __restrict__ V1,
                                             const float* __restrict__ V2,
                                             const float* __restrict__ ub,
                                             float* __restrict__ u1,
                                             float* __restrict__ u2p) {
  int row = blockIdx.x;   // b*N+n
  int g = threadIdx.x;    // 0..191
  const float* hr = h + (size_t)row * 64;  // uniform
  float a1 = 0.f, a2 = 0.f;
#pragma unroll
  for (int f = 0; f < 64; ++f) {
    float hv = hr[f];
    a1 += V1[g * 64 + f] * hv;
    a2 += V2[g * 64 + f] * hv;
  }
  u1[(size_t)row * G_ + g] = a1;
  u2p[(size_t)row * G_ + g] = a2 + ub[g];
}

// ---------- fusedT3: D^T = [W2e; whh](384x64)·edge^T via MFMA; edge read ONCE
// (residual recovered from B-frags via ds_bpermute); outputs buffered in regs
// and written as full 256B rows. Wave = 32 pairs, block = 4 waves = 128 pairs. ----------
__global__ __launch_bounds__(256, 3) void fusedT3(const float* __restrict__ edge,
                                                  const float* __restrict__ adj,
                                                  const unsigned short* __restrict__ BtW,
                                                  const float* __restrict__ u1,
                                                  const float* __restrict__ u2p,
                                                  const float* __restrict__ bih,
                                                  const float* __restrict__ bhh,
                                                  float* __restrict__ out) {
  __shared__ uint4 Bs4[3072];  // 48 KB: 384 rows x 128B, XOR-swizzled (R5-verified)
  char* Bc = (char*)Bs4;
  int tid = threadIdx.x;
  const uint4* src = (const uint4*)BtW;
#pragma unroll
  for (int it = 0; it < 12; ++it) {
    int c = tid + it * 256;          // 3072 chunks of 16B
    int row = c >> 3;
    *(uint4*)(Bc + row * 128 + (((c & 7) * 16) ^ ((row & 7) << 4))) = src[c];
  }
  __syncthreads();

  int lane = tid & 63, wave = tid >> 6;
  unsigned pbase = blockIdx.x * 128u + wave * 32u;
  int b = pbase >> 18;
  int iN = (pbase >> 9) & 511;
  int j0w = pbase & 511;
  int lr = lane & 15, lg = lane >> 4;

  // B-frags: lane (lr,lg) holds edge[np*16+lr][f = s*32 + lg*8 + q]
  bf16x8 efrag[2][2];
  float adjv[2];
#pragma unroll
  for (int np = 0; np < 2; ++np) {
    const float* er = edge + (size_t)(pbase + np * 16 + lr) * 64 + lg * 8;
    float tmp[8];
#pragma unroll
    for (int s = 0; s < 2; ++s) {
      *(float4*)tmp = *(const float4*)(er + s * 32);
      *(float4*)(tmp + 4) = *(const float4*)(er + s * 32 + 4);
      efrag[np][s] = pack8(tmp);
    }
    adjv[np] = adj[pbase + np * 16 + lr];
  }

  // bpermute source-lane addresses (byte addr = srclane*4); srclane = lr + 16*lg_src,
  // lg_src = (mg&1)*2 + (lg>>1)
  int addrE = (lr + 16 * (lg >> 1)) << 2;   // mg even
  int addrO = addrE + 128;                  // mg odd

  const float* u2r = u2p + ((size_t)(b * N_ + iN)) * G_;
  const float* u1b = u1 + ((size_t)(b * N_ + j0w)) * G_;

  f32x4 yo[2][4];

#pragma unroll
  for (int mg = 0; mg < 4; ++mg) {   // feature block: e = mg*16 + lg*4 + reg
    int e0 = mg * 16 + lg * 4;
    f32x4 acc[2][6];
    f32x4 zero = {0.f, 0.f, 0.f, 0.f};
#pragma unroll
    for (int np = 0; np < 2; ++np)
#pragma unroll
      for (int w = 0; w < 6; ++w) acc[np][w] = zero;

    const int tiles[6] = {mg, mg + 4, mg + 8, mg + 12, mg + 16, mg + 20};
#pragma unroll
    for (int s = 0; s < 2; ++s) {
      bf16x8 wf[6];
#pragma unroll
      for (int w = 0; w < 6; ++w) {
        int R = tiles[w] * 16 + lr;
        wf[w] = *(const bf16x8*)(Bc + R * 128 +
                                 ((s * 64 + lg * 16) ^ ((R & 7) << 4)));
      }
#pragma unroll
      for (int np = 0; np < 2; ++np)
#pragma unroll
        for (int w = 0; w < 6; ++w)
          acc[np][w] = __builtin_amdgcn_mfma_f32_16x16x32_bf16(
              wf[w], efrag[np][s], acc[np][w], 0, 0, 0);
    }

    // per-mg broadcast constants (L2-hot, tiny)
    f32x4 u2v0 = *(const f32x4*)(u2r + e0);
    f32x4 u2v1 = *(const f32x4*)(u2r + 64 + e0);
    f32x4 u2v2 = *(const f32x4*)(u2r + 128 + e0);
    f32x4 bc0 = *(const f32x4*)(bih + e0) + *(const f32x4*)(bhh + e0);
    f32x4 bc1 = *(const f32x4*)(bih + 64 + e0) + *(const f32x4*)(bhh + 64 + e0);
    f32x4 bi2 = *(const f32x4*)(bih + 128 + e0);
    f32x4 bh2 = *(const f32x4*)(bhh + 128 + e0);

#pragma unroll
    for (int np = 0; np < 2; ++np) {
      const float* u1r = u1b + (size_t)(np * 16 + lr) * G_;
      f32x4 u1v0 = *(const f32x4*)(u1r + e0);
      f32x4 u1v1 = *(const f32x4*)(u1r + 64 + e0);
      f32x4 u1v2 = *(const f32x4*)(u1r + 128 + e0);

      // residual edge values from efrag via LDS crossbar (no global re-read)
      union { bf16x8 v; int d[4]; } ef;
      ef.v = efrag[np][mg >> 1];
      int addr = (mg & 1) ? addrO : addrE;
      int r0 = __builtin_amdgcn_ds_bpermute(addr, ef.d[0]);
      int r1 = __builtin_amdgcn_ds_bpermute(addr, ef.d[1]);
      int r2 = __builtin_amdgcn_ds_bpermute(addr, ef.d[2]);
      int r3 = __builtin_amdgcn_ds_bpermute(addr, ef.d[3]);
      bool hi = (lg & 1);
      unsigned w0 = (unsigned)(hi ? r2 : r0);
      unsigned w1 = (unsigned)(hi ? r3 : r1);
      float eva[4];
      eva[0] = __uint_as_float(w0 << 16);
      eva[1] = __uint_as_float(w0 & 0xffff0000u);
      eva[2] = __uint_as_float(w1 << 16);
      eva[3] = __uint_as_float(w1 & 0xffff0000u);

      float a = adjv[np];
      f32x4 yv;
#pragma unroll
      for (int reg = 0; reg < 4; ++reg) {
        float s1 = a * (acc[np][0][reg] + u1v0[reg] + u2v0[reg]) + bc0[reg] +
                   acc[np][3][reg];
        float s2 = a * (acc[np][1][reg] + u1v1[reg] + u2v1[reg]) + bc1[reg] +
                   acc[np][4][reg];
        float gin = a * (acc[np][2][reg] + u1v2[reg] + u2v2[reg]) + bi2[reg];
        float ghn = acc[np][5][reg] + bh2[reg];
        float r = sigm(s1);
        float z = sigm(s2);
        float n = tanh_f(gin + r * ghn);
        float y = (1.f - z) * n + z * eva[reg];
        yv[reg] = y * sigm(y);
      }
      yo[np][mg] = yv;
    }
  }

  // tight full-row stores: each 256B out row written in 4 back-to-back float4s
#pragma unroll
  for (int np = 0; np < 2; ++np) {
    size_t P = pbase + np * 16 + lr;
    float* op = out + P * 64 + lg * 4;
#pragma unroll
    for (int mg = 0; mg < 4; ++mg)
      *(f32x4*)(op + mg * 16) = yo[np][mg];
  }
}

// ================= fallback fp32 path (used only if ws too small) =================
__global__ __launch_bounds__(64) void mkernelF(const float* __restrict__ edge,
                                               const float* __restrict__ adj,
                                               const float* __restrict__ Wlin,
                                               const float* __restrict__ blin,
                                               const float* __restrict__ h,
                                               float* __restrict__ mout) {
  size_t p = (size_t)blockIdx.x * 64 + threadIdx.x;
  int b = (int)(p >> 18), i = (int)((p >> 9) & 511), j = (int)(p & 511);
  float ed[E_], hj[E_], hi[E_];
  const float4* ep = (const float4*)(edge + p * E_);
  const float4* hjp = (const float4*)(h + ((size_t)(b * N_ + j)) * E_);
  const float4* hip = (const float4*)(h + ((size_t)(b * N_ + i)) * E_);
#pragma unroll
  for (int k = 0; k < E_ / 4; ++k) {
    float4 v = ep[k];
    ed[4 * k] = v.x; ed[4 * k + 1] = v.y; ed[4 * k + 2] = v.z; ed[4 * k + 3] = v.w;
    float4 a = hjp[k];
    hj[4 * k] = a.x; hj[4 * k + 1] = a.y; hj[4 * k + 2] = a.z; hj[4 * k + 3] = a.w;
    float4 u = hip[k];
    hi[4 * k] = u.x; hi[4 * k + 1] = u.y; hi[4 * k + 2] = u.z; hi[4 * k + 3] = u.w;
  }
  float av = adj[p];
  float* mo = mout + p * E_;
  for (int e = 0; e < E_; ++e) {
    const float* w = Wlin + e * LIN_IN_;
    float acc = blin[e];
#pragma unroll
    for (int k = 0; k < E_; ++k)
      acc += hj[k] * w[k] + ed[k] * w[64 + k] + hi[k] * w[128 + k];
    mo[e] = av * acc;
  }
}
__global__ __launch_bounds__(64) void gkernelF(const float* __restrict__ edge,
                                               const float* mbuf,
                                               const float* __restrict__ wih,
                                               const float* __restrict__ whh,
                                               const float* __restrict__ bih,
                                               const float* __restrict__ bhh,
                                               float* out) {
  size_t p = (size_t)blockIdx.x * 64 + threadIdx.x;
  float ed[E_], m[E_];
  const float4* ep = (const float4*)(edge + p * E_);
  const float4* mp = (const float4*)(mbuf + p * E_);
#pragma unroll
  for (int k = 0; k < E_ / 4; ++k) {
    float4 v = ep[k];
    ed[4 * k] = v.x; ed[4 * k + 1] = v.y; ed[4 * k + 2] = v.z; ed[4 * k + 3] = v.w;
    float4 u = mp[k];
    m[4 * k] = u.x; m[4 * k + 1] = u.y; m[4 * k + 2] = u.z; m[4 * k + 3] = u.w;
  }
  float* op = out + p * E_;
  for (int e = 0; e < E_; ++e) {
    const float* wr = wih + e * 64;
    const float* wz = wih + (64 + e) * 64;
    const float* wn = wih + (128 + e) * 64;
    const float* vr = whh + e * 64;
    const float* vz = whh + (64 + e) * 64;
    const float* vn = whh + (128 + e) * 64;
    float ir = bih[e], iz = bih[64 + e], inn = bih[128 + e];
    float hr = bhh[e], hz = bhh[64 + e], hn = bhh[128 + e];
#pragma unroll
    for (int k = 0; k < E_; ++k) {
      float mk = m[k], ek = ed[k];
      ir += mk * wr[k]; iz += mk * wz[k]; inn += mk * wn[k];
      hr += ek * vr[k]; hz += ek * vz[k]; hn += ek * vn[k];
    }
    float r = sigm(ir + hr);
    float z = sigm(iz + hz);
    float nv = tanh_f(inn + r * hn);
    float nh = (1.f - z) * nv + z * ed[e];
    op[e] = nh * sigm(nh);
  }
}

extern "C" void kernel_launch(void* const* d_in, const int* in_sizes, int n_in,
                              void* d_out, int out_size, void* d_ws, size_t ws_size,
                              hipStream_t stream) {
  const float* h    = (const float*)d_in[0];
  const float* edge = (const float*)d_in[1];
  const float* adj  = (const float*)d_in[2];
  const float* Wlin = (const float*)d_in[3];
  const float* blin = (const float*)d_in[4];
  const float* wih  = (const float*)d_in[5];
  const float* whh  = (const float*)d_in[6];
  const float* bih  = (const float*)d_in[7];
  const float* bhh  = (const float*)d_in[8];
  float* out = (float*)d_out;

  // ws layout (bytes): Bt bf16 49152 | V1 49152 | V2 49152 | ub 1024 | u1 786432 | u2p 786432
  const size_t OFF_V1 = 49152, OFF_V2 = 98304, OFF_UB = 147456,
               OFF_U1 = 148480, OFF_U2 = 148480 + 786432;
  const size_t WS_NEEDED = OFF_U2 + 786432;
  if (ws_size >= WS_NEEDED) {
    char* w = (char*)d_ws;
    unsigned short* Bt = (unsigned short*)w;
    float* V1 = (float*)(w + OFF_V1);
    float* V2 = (float*)(w + OFF_V2);
    float* ub = (float*)(w + OFF_UB);
    float* u1 = (float*)(w + OFF_U1);
    float* u2p = (float*)(w + OFF_U2);
    prep1<<<384, 64, 0, stream>>>(Wlin, blin, wih, whh, Bt, V1, V2, ub);
    prep2<<<B_ * N_, 192, 0, stream>>>(h, V1, V2, ub, u1, u2p);
    fusedT3<<<(B_ * N_ * N_) / 128, 256, 0, stream>>>(edge, adj, Bt, u1, u2p,
                                                      bih, bhh, out);
  } else {
    size_t npairs = (size_t)B_ * N_ * N_;
    int blocks = (int)(npairs / 64);
    mkernelF<<<blocks, 64, 0, stream>>>(edge, adj, Wlin, blin, h, out);
    gkernelF<<<blocks, 64, 0, stream>>>(edge, out, wih, whh, bih, bhh, out);
  }
}